// Round 13
// baseline (135.246 us; speedup 1.0000x reference)
//
#include <hip/hip_runtime.h>
#include <hip/hip_bf16.h>

#define NTOK 8192
#define DDIM 512
#define HDIM 1024
#define NEXP 8
#define TOPK 2

typedef __attribute__((ext_vector_type(8))) short short8;
typedef __attribute__((ext_vector_type(4))) float f32x4;

// fp32 -> bf16 round-to-nearest-even (finite inputs)
__device__ __forceinline__ short f2bf(float f) {
  union { float f; unsigned u; } v; v.f = f;
  unsigned r = v.u + 0x7fffu + ((v.u >> 16) & 1u);
  return (short)(r >> 16);
}
__device__ __forceinline__ float bf2f(short s) {
  union { unsigned u; float f; } v; v.u = ((unsigned)(unsigned short)s) << 16;
  return v.f;
}

__device__ __forceinline__ void async_lds16(const void* g, void* l) {
  __builtin_amdgcn_global_load_lds(
      (const __attribute__((address_space(1))) unsigned int*)g,
      (__attribute__((address_space(3))) unsigned int*)l,
      16, 0, 0);
}

// fast GELU: v * sigmoid(2u)  (~8 VALU ops); |diff vs erf GELU| < ~1e-3, thr 0.14
__device__ __forceinline__ float gelu_f(float v) {
  float u2 = v * v;
  float z = v * (-1.5957691216f - 0.0713548163f * u2);  // -2u
  float t = __expf(z);
  return v * __builtin_amdgcn_rcpf(1.f + t);
}

// ---------------- prep: weight transposes (blocks 0..8191) + router (blocks 8192..10239) ----------
__global__ __launch_bounds__(256) void prep_kernel(
    const float* __restrict__ w1, short* __restrict__ w1t,
    const float* __restrict__ w2, short* __restrict__ w2t,
    const float* __restrict__ x, const float* __restrict__ wg,
    float* __restrict__ out_logits, float* __restrict__ out_idx,
    float* __restrict__ out_w, short* __restrict__ xb, int* __restrict__ counts) {
  __shared__ float tile[32][33];
  int raw = blockIdx.x;
  if (raw < 8192) {
    int z = raw >> 9;
    int tile_id = raw & 511;
    int R = (z < 8) ? DDIM : HDIM;
    int C = (z < 8) ? HDIM : DDIM;
    const float* s = ((z < 8) ? w1 : w2) + (size_t)(z & 7) * DDIM * HDIM;
    short* d = ((z < 8) ? w1t : w2t) + (size_t)(z & 7) * DDIM * HDIM;
    int tc = (z < 8) ? (tile_id & 31) : (tile_id & 15);
    int tr = (z < 8) ? (tile_id >> 5) : (tile_id >> 4);
    int c0 = tc * 32, r0 = tr * 32;
    int tx = threadIdx.x & 31, ty = threadIdx.x >> 5;
#pragma unroll
    for (int i = 0; i < 4; ++i)
      tile[ty + i * 8][tx] = s[(size_t)(r0 + ty + i * 8) * C + c0 + tx];
    __syncthreads();
#pragma unroll
    for (int i = 0; i < 4; ++i)
      d[(size_t)(c0 + ty + i * 8) * R + r0 + tx] = f2bf(tile[tx][ty + i * 8]);
    return;
  }
  int rb = raw - 8192;
  if (rb == 0 && threadIdx.x < NEXP) counts[threadIdx.x] = 0;
  int wave = threadIdx.x >> 6;
  int lane = threadIdx.x & 63;
  int n = rb * 4 + wave;

  const float* xrow = x + (size_t)n * DDIM;
  const float4* xv = (const float4*)xrow;
  float4 xa = xv[lane * 2], xbv = xv[lane * 2 + 1];
  float xs[8] = {xa.x, xa.y, xa.z, xa.w, xbv.x, xbv.y, xbv.z, xbv.w};

  short8 xc;
#pragma unroll
  for (int j = 0; j < 8; ++j) xc[j] = f2bf(xs[j]);
  *(short8*)(xb + (size_t)n * DDIM + lane * 8) = xc;

  float acc[8] = {0, 0, 0, 0, 0, 0, 0, 0};
#pragma unroll
  for (int j = 0; j < 8; ++j) {
    const float4* wr = (const float4*)(wg + (size_t)(lane * 8 + j) * NEXP);
    float4 w0 = wr[0], w1v = wr[1];
    float xj = xs[j];
    acc[0] += xj * w0.x; acc[1] += xj * w0.y; acc[2] += xj * w0.z; acc[3] += xj * w0.w;
    acc[4] += xj * w1v.x; acc[5] += xj * w1v.y; acc[6] += xj * w1v.z; acc[7] += xj * w1v.w;
  }
#pragma unroll
  for (int m = 32; m >= 1; m >>= 1) {
#pragma unroll
    for (int e = 0; e < 8; ++e) acc[e] += __shfl_xor(acc[e], m);
  }
  if (lane == 0) {
#pragma unroll
    for (int e = 0; e < 8; ++e) out_logits[(size_t)n * NEXP + e] = acc[e];
    int i1 = 0; float v1 = acc[0];
#pragma unroll
    for (int e = 1; e < 8; ++e) if (acc[e] > v1) { v1 = acc[e]; i1 = e; }
    int i2 = -1; float v2 = -3.4e38f;
#pragma unroll
    for (int e = 0; e < 8; ++e) if (e != i1 && acc[e] > v2) { v2 = acc[e]; i2 = e; }
    float ex = expf(v2 - v1);
    float s = 1.f / (1.f + ex);
    out_idx[n * 2] = (float)i1; out_idx[n * 2 + 1] = (float)i2;
    out_w[n * 2] = s; out_w[n * 2 + 1] = ex * s;
  }
}

// ---------------- build per-expert token lists (wave-aggregated atomics) ----------------
__global__ __launch_bounds__(512) void build_lists(
    const float* __restrict__ idxf,
    int* __restrict__ counts, int* __restrict__ tok_list, int* __restrict__ slot_enc) {
  int t = blockIdx.x * 512 + threadIdx.x;
  int lane = threadIdx.x & 63;
  float2 iv = *(const float2*)(idxf + (size_t)t * 2);
  int es[2] = {(int)iv.x, (int)iv.y};
#pragma unroll
  for (int s = 0; s < 2; ++s) {
    int e = es[s];
#pragma unroll
    for (int ex = 0; ex < NEXP; ++ex) {
      unsigned long long m = __ballot(e == ex);
      if (e == ex) {
        int leader = __ffsll(m) - 1;
        int base = 0;
        if (lane == leader) base = atomicAdd(&counts[ex], __popcll(m));
        base = __shfl(base, leader);
        int rank = __popcll(m & ((1ull << lane) - 1ull));
        tok_list[ex * NTOK + base + rank] = t;
        slot_enc[t * 2 + s] = (ex << 16) | (base + rank);
      }
    }
  }
}

// =====================================================================================
// GEMM1 (8-phase): 256x256 tile, 8 waves (128x64 out each), BK=32, 2 LDS K-tile buffers
// (64KB, linear — BK=32 rows are conflict-free for b128 frag reads), counted vmcnt(2)
// drains only at phases 3/7, per-phase {ds_read || 1 half-tile stage -> BAR -> lgkm0 ->
// 8 MFMA -> BAR}. XCD x owns expert x. Derivation invariants in comments.
// =====================================================================================
__global__ __launch_bounds__(512, 2) void expert_gemm1(
    const short* __restrict__ xb, const short* __restrict__ w1t,
    const float* __restrict__ b1, short* __restrict__ hbuf,
    const int* __restrict__ ctrl, const int* __restrict__ tok_list) {
  int raw = blockIdx.x;          // 1024 blocks; raw&7 = expert = XCD
  int e = raw & 7;
  int rem = raw >> 3;            // [0,128)
  int mt = rem >> 2;             // [0,32): covers ce up to 8192
  int nt = rem & 3;              // H/256
  int ce = ctrl[e];
  int m0 = mt * 256;
  if (m0 >= ce) return;
  int offe = 0;
#pragma unroll
  for (int i = 0; i < NEXP; ++i) offe += (i < e) ? ctrl[i] : 0;

  // buf b at smem + b*32768: A[256][32]bf16 (16KB) | B[256][32]bf16 (16KB)
  __shared__ char smem[65536];

  int tid = threadIdx.x;
  int w = tid >> 6;
  int lane = tid & 63;

  // ---- staging: half-tile h (rows h*128..h*128+128) = 1 instr/thread (512x16B = 8KB)
  int srow = lane >> 2;          // row within wave's 16-row group
  int schunk = lane & 3;         // 16B chunk within 64B row
  const short* aptr[2]; const short* bptr[2]; int adst[2];
#pragma unroll
  for (int h = 0; h < 2; ++h) {
    int r = h * 128 + w * 16 + srow;     // row within 256-row tile
    int ga = m0 + r; if (ga >= ce) ga = ce - 1;
    aptr[h] = xb + (size_t)tok_list[e * NTOK + ga] * DDIM + schunk * 8;
    bptr[h] = w1t + ((size_t)e * HDIM + nt * 256 + r) * DDIM + schunk * 8;
    adst[h] = (h * 128 + w * 16) * 64;   // bytes; +lane*16 by HW
  }
#define STGA(h, t, buf) async_lds16(aptr[h] + (t) * 32, smem + (buf) * 32768 + adst[h])
#define STGB(h, t, buf) async_lds16(bptr[h] + (t) * 32, smem + (buf) * 32768 + 16384 + adst[h])

  // ---- fragment geometry
  int wm = (w >> 2) * 128;       // M-half
  int wnq = (w & 3) * 64;        // N-quarter
  int lr = lane & 15;
  int kh16 = (lane >> 4) * 16;   // byte offset of 16B k-chunk
#define RA(i_, base) (*(const short8*)((base) + (wm + (i_) * 16 + lr) * 64 + kh16))
#define RB(j_, base) (*(const short8*)((base) + 16384 + (wnq + (j_) * 16 + lr) * 64 + kh16))

  f32x4 acc[8][4];
#pragma unroll
  for (int i = 0; i < 8; ++i)
#pragma unroll
    for (int j = 0; j < 4; ++j) acc[i][j] = (f32x4){0.f, 0.f, 0.f, 0.f};

  // bias hoist (latency hides under K-loop)
  int colb = nt * 256 + wnq;
  float bb[4];
#pragma unroll
  for (int j = 0; j < 4; ++j) bb[j] = b1[e * HDIM + colb + j * 16 + lr];

#define MFMA8(q, a0_, a1_)                                                          \
  do {                                                                              \
    acc[2*(q)][0]   = __builtin_amdgcn_mfma_f32_16x16x32_bf16(a0_, b0, acc[2*(q)][0],   0,0,0); \
    acc[2*(q)][1]   = __builtin_amdgcn_mfma_f32_16x16x32_bf16(a0_, b1, acc[2*(q)][1],   0,0,0); \
    acc[2*(q)][2]   = __builtin_amdgcn_mfma_f32_16x16x32_bf16(a0_, b2, acc[2*(q)][2],   0,0,0); \
    acc[2*(q)][3]   = __builtin_amdgcn_mfma_f32_16x16x32_bf16(a0_, b3, acc[2*(q)][3],   0,0,0); \
    acc[2*(q)+1][0] = __builtin_amdgcn_mfma_f32_16x16x32_bf16(a1_, b0, acc[2*(q)+1][0], 0,0,0); \
    acc[2*(q)+1][1] = __builtin_amdgcn_mfma_f32_16x16x32_bf16(a1_, b1, acc[2*(q)+1][1], 0,0,0); \
    acc[2*(q)+1][2] = __builtin_amdgcn_mfma_f32_16x16x32_bf16(a1_, b2, acc[2*(q)+1][2], 0,0,0); \
    acc[2*(q)+1][3] = __builtin_amdgcn_mfma_f32_16x16x32_bf16(a1_, b3, acc[2*(q)+1][3], 0,0,0); \
  } while (0)

#define SYNC_IN()                                              \
  asm volatile("s_barrier" ::: "memory");                      \
  asm volatile("s_waitcnt lgkmcnt(0)" ::: "memory");           \
  __builtin_amdgcn_sched_barrier(0);                           \
  __builtin_amdgcn_s_setprio(1)
#define SYNC_OUT()                                             \
  __builtin_amdgcn_s_setprio(0);                               \
  asm volatile("s_barrier" ::: "memory")
#define SYNC_OUT_DRAIN2()                                      \
  __builtin_amdgcn_s_setprio(0);                               \
  asm volatile("s_waitcnt vmcnt(2)\n\ts_barrier" ::: "memory")
#define SYNC_OUT_DRAIN0()                                      \
  __builtin_amdgcn_s_setprio(0);                               \
  asm volatile("s_waitcnt vmcnt(0)\n\ts_barrier" ::: "memory")

  // ---- prologue: tile0 -> buf0 (B then A), B-halves of tile1 -> buf1.
  // vmcnt(2) retires the 4 oldest (= all of tile0); carry-in = {B0,B1(tile1)}.
  STGB(0, 0, 0); STGB(1, 0, 0); STGA(0, 0, 0); STGA(1, 0, 0);
  STGB(0, 1, 1); STGB(1, 1, 1);
  asm volatile("s_waitcnt vmcnt(2)\n\ts_barrier" ::: "memory");

  // ---- main loop: iter i reads tile 2i (buf0, ph0-3) and tile 2i+1 (buf1, ph4-7).
  // WAR invariant: a stage issued in phase p is safe for any region last READ in a
  // phase <= p-1, because those reads were serviced (lgkmcnt(0)) before a barrier
  // that precedes this issue. FIFO drains: at ph3/ph7 exactly 6 outstanding;
  // vmcnt(2) retires precisely the 4 loads of the tile read next.
  const char* BUF0 = smem;
  const char* BUF1 = smem + 32768;
#pragma unroll
  for (int i = 0; i < 8; ++i) {
    short8 b0, b1, b2, b3, a0, a1;
    // ph0: b-frags(tile 2i) + a(0,1); stage A0(2i+1)->buf1 (buf1.A readers done prev ph7)
    b0 = RB(0, BUF0); b1 = RB(1, BUF0); b2 = RB(2, BUF0); b3 = RB(3, BUF0);
    a0 = RA(0, BUF0); a1 = RA(1, BUF0);
    STGA(0, 2 * i + 1, 1);
    SYNC_IN(); MFMA8(0, a0, a1); SYNC_OUT();
    // ph1
    a0 = RA(2, BUF0); a1 = RA(3, BUF0);
    STGA(1, 2 * i + 1, 1);
    SYNC_IN(); MFMA8(1, a0, a1); SYNC_OUT();
    // ph2: stage B0(2i+2)->buf0 (buf0.B last read ph0)
    a0 = RA(4, BUF0); a1 = RA(5, BUF0);
    if (i < 7) STGB(0, 2 * i + 2, 0);
    SYNC_IN(); MFMA8(2, a0, a1); SYNC_OUT();
    // ph3: stage B1(2i+2)->buf0; drain: tile(2i+1) must be landed before ph4 reads
    a0 = RA(6, BUF0); a1 = RA(7, BUF0);
    if (i < 7) STGB(1, 2 * i + 2, 0);
    SYNC_IN(); MFMA8(3, a0, a1);
    if (i < 7) { SYNC_OUT_DRAIN2(); } else { SYNC_OUT_DRAIN0(); }
    // ph4: b-frags(tile 2i+1) + a(0,1); stage A0(2i+2)->buf0 (buf0.A last read ph3)
    b0 = RB(0, BUF1); b1 = RB(1, BUF1); b2 = RB(2, BUF1); b3 = RB(3, BUF1);
    a0 = RA(0, BUF1); a1 = RA(1, BUF1);
    if (i < 7) STGA(0, 2 * i + 2, 0);
    SYNC_IN(); MFMA8(0, a0, a1); SYNC_OUT();
    // ph5
    a0 = RA(2, BUF1); a1 = RA(3, BUF1);
    if (i < 7) STGA(1, 2 * i + 2, 0);
    SYNC_IN(); MFMA8(1, a0, a1); SYNC_OUT();
    // ph6: stage B0(2i+3)->buf1 (buf1.B last read ph4)
    a0 = RA(4, BUF1); a1 = RA(5, BUF1);
    if (i < 7) STGB(0, 2 * i + 3, 1);
    SYNC_IN(); MFMA8(2, a0, a1); SYNC_OUT();
    // ph7: stage B1(2i+3)->buf1; drain: tile(2i+2) landed before next ph0
    a0 = RA(6, BUF1); a1 = RA(7, BUF1);
    if (i < 7) STGB(1, 2 * i + 3, 1);
    SYNC_IN(); MFMA8(3, a0, a1);
    if (i < 7) { SYNC_OUT_DRAIN2(); } else { SYNC_OUT_DRAIN0(); }
  }
#undef STGA
#undef STGB
#undef RA
#undef RB
  __syncthreads();  // K-loop LDS dead; epilogue reuses it

  // ---- epilogue: 4 passes of 32 rows; GELU -> bf16 -> per-wave [32][68] -> short8 stores
  short* ep = (short*)(smem + w * 4352);
#pragma unroll
  for (int p = 0; p < 4; ++p) {
#pragma unroll
    for (int ii = 0; ii < 2; ++ii) {
#pragma unroll
      for (int j = 0; j < 4; ++j) {
#pragma unroll
        for (int q = 0; q < 4; ++q) {
          int rl = ii * 16 + (lane >> 4) * 4 + q;
          ep[rl * 68 + j * 16 + lr] = f2bf(gelu_f(acc[p * 2 + ii][j][q] + bb[j]));
        }
      }
    }
    __syncthreads();
#pragma unroll
    for (int s = 0; s < 4; ++s) {
      int idx = s * 64 + lane;
      int rl = idx >> 3;
      int c8 = (idx & 7) * 8;
      int gidx = m0 + wm + p * 32 + rl;
      if (gidx < ce) {
        *(short8*)&hbuf[(size_t)(offe + gidx) * HDIM + colb + c8] = *(short8*)&ep[rl * 68 + c8];
      }
    }
    __syncthreads();
  }
}

// ---------------- GEMM2: ybuf = (h @ W2[e] + b2[e]) in bf16 (proven R12 structure) ----------------
__global__ __launch_bounds__(256) void expert_gemm2(
    const short* __restrict__ hbuf, const short* __restrict__ w2t,
    const float* __restrict__ b2, short* __restrict__ ybuf,
    const int* __restrict__ ctrl) {
  int raw = blockIdx.x;
  int bid = (raw & 7) * 256 + (raw >> 3);  // XCD x owns expert x
  int e = bid >> 8;
  int rem = bid & 255;
  int mt = rem >> 2;
  int nt = rem & 3;
  int ce = ctrl[e];
  int m0 = mt * 128;
  if (m0 >= ce) return;
  int offe = 0;
#pragma unroll
  for (int i = 0; i < NEXP; ++i) offe += (i < e) ? ctrl[i] : 0;

  __shared__ char smem[34816];

  int tid = threadIdx.x;
  int wave = tid >> 6;
  int lane = tid & 63;

  int sr = tid >> 2;
  int kc = (((tid & 3) ^ ((sr >> 1) & 3)) * 8);
  int ia = m0 + sr;      if (ia >= ce) ia = ce - 1;
  int ib = m0 + sr + 64; if (ib >= ce) ib = ce - 1;
  const short* gA0 = hbuf + (size_t)(offe + ia) * HDIM + kc;
  const short* gA1 = hbuf + (size_t)(offe + ib) * HDIM + kc;
  const short* gB0 = w2t + ((size_t)e * DDIM + nt * 128 + sr) * HDIM + kc;
  const short* gB1 = gB0 + (size_t)64 * HDIM;

  f32x4 acc[4][4];
#pragma unroll
  for (int i = 0; i < 4; ++i)
#pragma unroll
    for (int j = 0; j < 4; ++j) acc[i][j] = (f32x4){0.f, 0.f, 0.f, 0.f};

  int wm = (wave >> 1) * 64;
  int wn = (wave & 1) * 64;
  int lr = lane & 15;
  int kswz = ((lane >> 4) * 8) ^ (((lr >> 1) & 3) << 3);

  int colb = nt * 128 + wn;
  float bb[4];
#pragma unroll
  for (int j = 0; j < 4; ++j) bb[j] = b2[e * DDIM + colb + j * 16 + lr];

#define STAGE2(t) do {                                                  \
    int _k = (t) * 32;                                                  \
    char* _lA = smem + (((t) & 1) << 14) + wave * 1024;                 \
    char* _lB = _lA + 8192;                                             \
    async_lds16(gA0 + _k, _lA); async_lds16(gA1 + _k, _lA + 4096);      \
    async_lds16(gB0 + _k, _lB); async_lds16(gB1 + _k, _lB + 4096);      \
  } while (0)

  STAGE2(0);
#pragma unroll
  for (int t = 0; t < 32; ++t) {
    asm volatile("s_waitcnt vmcnt(0)\n\ts_barrier" ::: "memory");
    if (t + 1 < 32) STAGE2(t + 1);
    const short* As = (const short*)(smem + ((t & 1) << 14));
    const short* Bs = As + 4096;
    short8 a[4], b[4];
#pragma unroll
    for (int i = 0; i < 4; ++i) a[i] = *(const short8*)&As[(wm + i * 16 + lr) * 32 + kswz];
#pragma unroll
    for (int j = 0; j < 4; ++j) b[j] = *(const short8*)&Bs[(wn + j * 16 + lr) * 32 + kswz];
    __builtin_amdgcn_s_setprio(1);
#pragma unroll
    for (int i = 0; i < 4; ++i)
#pragma unroll
      for (int j = 0; j < 4; ++j)
        acc[i][j] = __builtin_amdgcn_mfma_f32_16x16x32_bf16(a[i], b[j], acc[i][j], 0, 0, 0);
    __builtin_amdgcn_s_setprio(0);
    asm volatile("s_waitcnt lgkmcnt(0)" ::: "memory");
  }
#undef STAGE2
  __syncthreads();

  short* ep = (short*)(smem + wave * 8704);
#pragma unroll
  for (int j = 0; j < 4; ++j) {
#pragma unroll
    for (int i = 0; i < 4; ++i) {
#pragma unroll
      for (int q = 0; q < 4; ++q) {
        int rl = i * 16 + (lane >> 4) * 4 + q;
        ep[rl * 68 + j * 16 + lr] = f2bf(acc[i][j][q] + bb[j]);
      }
    }
  }
  __syncthreads();
#pragma unroll
  for (int s = 0; s < 8; ++s) {
    int idx = s * 64 + lane;
    int rl = idx >> 3;
    int c8 = (idx & 7) * 8;
    int gidx = m0 + wm + rl;
    if (gidx < ce) {
      *(short8*)&ybuf[(size_t)(offe + gidx) * DDIM + colb + c8] = *(short8*)&ep[rl * 68 + c8];
    }
  }
}

// ---------------- combine: out[n] = w0*ybuf[slot0] + w1*ybuf[slot1] ----------------
__global__ __launch_bounds__(256) void combine_kernel(
    const short* __restrict__ ybuf, const int* __restrict__ slot_enc,
    const float* __restrict__ wf, const int* __restrict__ ctrl,
    float* __restrict__ out) {
  int wave = threadIdx.x >> 6;
  int lane = threadIdx.x & 63;
  int n = blockIdx.x * 4 + wave;
  int s0 = slot_enc[n * 2], s1 = slot_enc[n * 2 + 1];
  float w0 = wf[n * 2], w1 = wf[n * 2 + 1];
  int e0 = s0 >> 16, e1 = s1 >> 16;
  int off0 = 0, off1 = 0;
#pragma unroll
  for (int i = 0; i < NEXP; ++i) {
    int c = ctrl[i];
    off0 += (i < e0) ? c : 0;
    off1 += (i < e1) ? c : 0;
  }
  int r0 = off0 + (s0 & 0xffff);
  int r1 = off1 + (s1 & 0xffff);
  short8 a = *(const short8*)&ybuf[(size_t)r0 * DDIM + lane * 8];
  short8 b = *(const short8*)&ybuf[(size_t)r1 * DDIM + lane * 8];
  float r[8];
#pragma unroll
  for (int k = 0; k < 8; ++k) r[k] = w0 * bf2f(a[k]) + w1 * bf2f(b[k]);
  float4 o0 = {r[0], r[1], r[2], r[3]};
  float4 o1 = {r[4], r[5], r[6], r[7]};
  *(float4*)&out[(size_t)n * DDIM + lane * 8] = o0;
  *(float4*)&out[(size_t)n * DDIM + lane * 8 + 4] = o1;
}

extern "C" void kernel_launch(void* const* d_in, const int* in_sizes, int n_in,
                              void* d_out, int out_size, void* d_ws, size_t ws_size,
                              hipStream_t stream) {
  const float* x  = (const float*)d_in[0];
  const float* wg = (const float*)d_in[1];
  const float* w1 = (const float*)d_in[2];
  const float* b1 = (const float*)d_in[3];
  const float* w2 = (const float*)d_in[4];
  const float* b2 = (const float*)d_in[5];
  float* out = (float*)d_out;

  char* ws = (char*)d_ws;
  int*   ctrl = (int*)ws;                    // [0..7] counts
  int*   tok  = (int*)(ws + 1024);           // 256 KB
  int*   slot = (int*)(ws + 263168);         // 64 KB
  short* xb   = (short*)(ws + 328704);       // 8 MB
  short* w1t  = (short*)(ws + 8717312);      // 8 MB [E][H][D]
  short* w2t  = (short*)(ws + 17105920);     // 8 MB [E][D][H]
  short* hb   = (short*)(ws + 25494528);     // 32 MB
  short* yb   = (short*)(ws + 328704);       // 16 MB, ALIASES xb+w1t (dead by GEMM2)

  float* out_logits = out + (size_t)NTOK * DDIM;
  float* out_idx = out_logits + (size_t)NTOK * NEXP;
  float* out_w = out_idx + (size_t)NTOK * TOPK;

  prep_kernel<<<10240, 256, 0, stream>>>(w1, w1t, w2, w2t, x, wg,
                                         out_logits, out_idx, out_w, xb, ctrl);
  build_lists<<<16, 512, 0, stream>>>(out_idx, ctrl, tok, slot);

  expert_gemm1<<<1024, 512, 0, stream>>>(xb, w1t, b1, hb, ctrl, tok);
  expert_gemm2<<<2048, 256, 0, stream>>>(hb, w2t, b2, yb, ctrl);
  combine_kernel<<<2048, 256, 0, stream>>>(yb, slot, out_w, ctrl, out);
}

// Round 14
// 123.079 us; speedup vs baseline: 1.0989x; 1.0989x over previous
//
#include <hip/hip_runtime.h>
#include <hip/hip_bf16.h>

#define NTOK 8192
#define DDIM 512
#define HDIM 1024
#define NEXP 8
#define TOPK 2

typedef __attribute__((ext_vector_type(8))) short short8;
typedef __attribute__((ext_vector_type(4))) float f32x4;

// fp32 -> bf16 round-to-nearest-even (finite inputs)
__device__ __forceinline__ short f2bf(float f) {
  union { float f; unsigned u; } v; v.f = f;
  unsigned r = v.u + 0x7fffu + ((v.u >> 16) & 1u);
  return (short)(r >> 16);
}
__device__ __forceinline__ float bf2f(short s) {
  union { unsigned u; float f; } v; v.u = ((unsigned)(unsigned short)s) << 16;
  return v.f;
}

__device__ __forceinline__ void async_lds16(const void* g, void* l) {
  __builtin_amdgcn_global_load_lds(
      (const __attribute__((address_space(1))) unsigned int*)g,
      (__attribute__((address_space(3))) unsigned int*)l,
      16, 0, 0);
}

// fast GELU: v * sigmoid(2u)  (~8 VALU ops); |diff vs erf GELU| < ~1e-3, thr 0.14
__device__ __forceinline__ float gelu_f(float v) {
  float u2 = v * v;
  float z = v * (-1.5957691216f - 0.0713548163f * u2);  // -2u
  float t = __expf(z);
  return v * __builtin_amdgcn_rcpf(1.f + t);
}

// ---------------- prep: weight transposes (blocks 0..8191) + router (blocks 8192..10239) ----------
__global__ __launch_bounds__(256) void prep_kernel(
    const float* __restrict__ w1, short* __restrict__ w1t,
    const float* __restrict__ w2, short* __restrict__ w2t,
    const float* __restrict__ x, const float* __restrict__ wg,
    float* __restrict__ out_logits, float* __restrict__ out_idx,
    float* __restrict__ out_w, short* __restrict__ xb, int* __restrict__ counts) {
  __shared__ float tile[32][33];
  int raw = blockIdx.x;
  if (raw < 8192) {
    int z = raw >> 9;
    int tile_id = raw & 511;
    int R = (z < 8) ? DDIM : HDIM;
    int C = (z < 8) ? HDIM : DDIM;
    const float* s = ((z < 8) ? w1 : w2) + (size_t)(z & 7) * DDIM * HDIM;
    short* d = ((z < 8) ? w1t : w2t) + (size_t)(z & 7) * DDIM * HDIM;
    int tc = (z < 8) ? (tile_id & 31) : (tile_id & 15);
    int tr = (z < 8) ? (tile_id >> 5) : (tile_id >> 4);
    int c0 = tc * 32, r0 = tr * 32;
    int tx = threadIdx.x & 31, ty = threadIdx.x >> 5;
#pragma unroll
    for (int i = 0; i < 4; ++i)
      tile[ty + i * 8][tx] = s[(size_t)(r0 + ty + i * 8) * C + c0 + tx];
    __syncthreads();
#pragma unroll
    for (int i = 0; i < 4; ++i)
      d[(size_t)(c0 + ty + i * 8) * R + r0 + tx] = f2bf(tile[tx][ty + i * 8]);
    return;
  }
  int rb = raw - 8192;
  if (rb == 0 && threadIdx.x < NEXP) counts[threadIdx.x] = 0;
  int wave = threadIdx.x >> 6;
  int lane = threadIdx.x & 63;
  int n = rb * 4 + wave;

  const float* xrow = x + (size_t)n * DDIM;
  const float4* xv = (const float4*)xrow;
  float4 xa = xv[lane * 2], xbv = xv[lane * 2 + 1];
  float xs[8] = {xa.x, xa.y, xa.z, xa.w, xbv.x, xbv.y, xbv.z, xbv.w};

  short8 xc;
#pragma unroll
  for (int j = 0; j < 8; ++j) xc[j] = f2bf(xs[j]);
  *(short8*)(xb + (size_t)n * DDIM + lane * 8) = xc;

  float acc[8] = {0, 0, 0, 0, 0, 0, 0, 0};
#pragma unroll
  for (int j = 0; j < 8; ++j) {
    const float4* wr = (const float4*)(wg + (size_t)(lane * 8 + j) * NEXP);
    float4 w0 = wr[0], w1v = wr[1];
    float xj = xs[j];
    acc[0] += xj * w0.x; acc[1] += xj * w0.y; acc[2] += xj * w0.z; acc[3] += xj * w0.w;
    acc[4] += xj * w1v.x; acc[5] += xj * w1v.y; acc[6] += xj * w1v.z; acc[7] += xj * w1v.w;
  }
#pragma unroll
  for (int m = 32; m >= 1; m >>= 1) {
#pragma unroll
    for (int e = 0; e < 8; ++e) acc[e] += __shfl_xor(acc[e], m);
  }
  if (lane == 0) {
#pragma unroll
    for (int e = 0; e < 8; ++e) out_logits[(size_t)n * NEXP + e] = acc[e];
    int i1 = 0; float v1 = acc[0];
#pragma unroll
    for (int e = 1; e < 8; ++e) if (acc[e] > v1) { v1 = acc[e]; i1 = e; }
    int i2 = -1; float v2 = -3.4e38f;
#pragma unroll
    for (int e = 0; e < 8; ++e) if (e != i1 && acc[e] > v2) { v2 = acc[e]; i2 = e; }
    float ex = expf(v2 - v1);
    float s = 1.f / (1.f + ex);
    out_idx[n * 2] = (float)i1; out_idx[n * 2 + 1] = (float)i2;
    out_w[n * 2] = s; out_w[n * 2 + 1] = ex * s;
  }
}

// ---------------- build per-expert token lists (wave-aggregated atomics) ----------------
__global__ __launch_bounds__(512) void build_lists(
    const float* __restrict__ idxf,
    int* __restrict__ counts, int* __restrict__ tok_list, int* __restrict__ slot_enc) {
  int t = blockIdx.x * 512 + threadIdx.x;
  int lane = threadIdx.x & 63;
  float2 iv = *(const float2*)(idxf + (size_t)t * 2);
  int es[2] = {(int)iv.x, (int)iv.y};
#pragma unroll
  for (int s = 0; s < 2; ++s) {
    int e = es[s];
#pragma unroll
    for (int ex = 0; ex < NEXP; ++ex) {
      unsigned long long m = __ballot(e == ex);
      if (e == ex) {
        int leader = __ffsll(m) - 1;
        int base = 0;
        if (lane == leader) base = atomicAdd(&counts[ex], __popcll(m));
        base = __shfl(base, leader);
        int rank = __popcll(m & ((1ull << lane) - 1ull));
        tok_list[ex * NTOK + base + rank] = t;
        slot_enc[t * 2 + s] = (ex << 16) | (base + rank);
      }
    }
  }
}

// ---------------- GEMM1: h = GELU(gather(x) @ W1[e] + b1[e]) -> bf16 hbuf ----------------
// R12-proven 128x128 structure; LDS shrunk to 32KB (2-pass epilogue) -> 5 blocks/CU.
__global__ __launch_bounds__(256) void expert_gemm1(
    const short* __restrict__ xb, const short* __restrict__ w1t,
    const float* __restrict__ b1, short* __restrict__ hbuf,
    const int* __restrict__ ctrl, const int* __restrict__ tok_list) {
  int raw = blockIdx.x;
  int bid = (raw & 7) * 512 + (raw >> 3);  // bijective: XCD x owns expert x
  int e = bid >> 9;
  int rem = bid & 511;
  int mt = rem >> 3;
  int nt = rem & 7;
  int ce = ctrl[e];
  int m0 = mt * 128;
  if (m0 >= ce) return;
  int offe = 0;
#pragma unroll
  for (int i = 0; i < NEXP; ++i) offe += (i < e) ? ctrl[i] : 0;

  // LDS: 2 staging buffers x 16KB (As 8K | Bs 8K) = 32KB -> 5 blocks/CU.
  // Epilogue reuses [0, 4*4352) in 2 passes of 32 rows.
  __shared__ char smem[32768];

  int tid = threadIdx.x;
  int wave = tid >> 6;
  int lane = tid & 63;

  int sr = tid >> 2;
  // Pre-swizzled source: lane writes LDS chunk (sr, tid&3); fetch the global chunk
  // that belongs there under involution chunk^=((row>>1)&3)
  int kc = (((tid & 3) ^ ((sr >> 1) & 3)) * 8);
  int ia = m0 + sr;      if (ia >= ce) ia = ce - 1;
  int ib = m0 + sr + 64; if (ib >= ce) ib = ce - 1;
  const short* gA0 = xb + (size_t)tok_list[e * NTOK + ia] * DDIM + kc;
  const short* gA1 = xb + (size_t)tok_list[e * NTOK + ib] * DDIM + kc;
  const short* gB0 = w1t + ((size_t)e * HDIM + nt * 128 + sr) * DDIM + kc;
  const short* gB1 = gB0 + (size_t)64 * DDIM;

  f32x4 acc[4][4];
#pragma unroll
  for (int i = 0; i < 4; ++i)
#pragma unroll
    for (int j = 0; j < 4; ++j) acc[i][j] = (f32x4){0.f, 0.f, 0.f, 0.f};

  int wm = (wave >> 1) * 64;
  int wn = (wave & 1) * 64;
  int lr = lane & 15;
  int kswz = ((lane >> 4) * 8) ^ (((lr >> 1) & 3) << 3);

  // Hoist bias loads: latency hides under the K-loop.
  int colb = nt * 128 + wn;
  float bb[4];
#pragma unroll
  for (int j = 0; j < 4; ++j) bb[j] = b1[e * HDIM + colb + j * 16 + lr];

#define STAGE1(t) do {                                                  \
    int _k = (t) * 32;                                                  \
    char* _lA = smem + (((t) & 1) << 14) + wave * 1024;                 \
    char* _lB = _lA + 8192;                                             \
    async_lds16(gA0 + _k, _lA); async_lds16(gA1 + _k, _lA + 4096);      \
    async_lds16(gB0 + _k, _lB); async_lds16(gB1 + _k, _lB + 4096);      \
  } while (0)

  STAGE1(0);
#pragma unroll
  for (int t = 0; t < 16; ++t) {
    // Tile t's DMA (all waves) landed once every wave passes this barrier.
    asm volatile("s_waitcnt vmcnt(0)\n\ts_barrier" ::: "memory");
    // Overwriting buf[(t+1)&1] (read at t-1) is safe: every wave drained
    // lgkmcnt(0) at the end of iter t-1, BEFORE arriving at the barrier above.
    if (t + 1 < 16) STAGE1(t + 1);
    const short* As = (const short*)(smem + ((t & 1) << 14));
    const short* Bs = As + 4096;
    short8 a[4], b[4];
#pragma unroll
    for (int i = 0; i < 4; ++i) a[i] = *(const short8*)&As[(wm + i * 16 + lr) * 32 + kswz];
#pragma unroll
    for (int j = 0; j < 4; ++j) b[j] = *(const short8*)&Bs[(wn + j * 16 + lr) * 32 + kswz];
    // Compiler emits counted lgkmcnt before each first use (read/MFMA interleave).
    __builtin_amdgcn_s_setprio(1);
#pragma unroll
    for (int i = 0; i < 4; ++i)
#pragma unroll
      for (int j = 0; j < 4; ++j)
        acc[i][j] = __builtin_amdgcn_mfma_f32_16x16x32_bf16(a[i], b[j], acc[i][j], 0, 0, 0);
    __builtin_amdgcn_s_setprio(0);
    // Invariant: this wave's ds_reads are SERVICED before it reaches the next barrier.
    asm volatile("s_waitcnt lgkmcnt(0)" ::: "memory");
  }
#undef STAGE1
  __syncthreads();  // all K-loop reads done before epilogue reuses smem

  // ---- 2-pass LDS epilogue (32 rows/pass): GELU -> bf16 -> [32][68]/wave -> short8 stores
  short* ep = (short*)(smem + wave * 4352);
#pragma unroll
  for (int p = 0; p < 2; ++p) {
#pragma unroll
    for (int ii = 0; ii < 2; ++ii) {
#pragma unroll
      for (int j = 0; j < 4; ++j) {
#pragma unroll
        for (int q = 0; q < 4; ++q) {
          int rl = ii * 16 + (lane >> 4) * 4 + q;
          ep[rl * 68 + j * 16 + lr] = f2bf(gelu_f(acc[p * 2 + ii][j][q] + bb[j]));
        }
      }
    }
    __syncthreads();
#pragma unroll
    for (int s = 0; s < 4; ++s) {
      int idx = s * 64 + lane;
      int rl = idx >> 3;
      int c8 = (idx & 7) * 8;
      int gidx = m0 + wm + p * 32 + rl;
      if (gidx < ce) {
        *(short8*)&hbuf[(size_t)(offe + gidx) * HDIM + colb + c8] = *(short8*)&ep[rl * 68 + c8];
      }
    }
    __syncthreads();
  }
}

// ---------------- GEMM2: ybuf = (h @ W2[e] + b2[e]) in bf16 (per expert-slot row) ----------------
__global__ __launch_bounds__(256) void expert_gemm2(
    const short* __restrict__ hbuf, const short* __restrict__ w2t,
    const float* __restrict__ b2, short* __restrict__ ybuf,
    const int* __restrict__ ctrl) {
  int raw = blockIdx.x;
  int bid = (raw & 7) * 256 + (raw >> 3);  // XCD x owns expert x
  int e = bid >> 8;
  int rem = bid & 255;
  int mt = rem >> 2;
  int nt = rem & 3;
  int ce = ctrl[e];
  int m0 = mt * 128;
  if (m0 >= ce) return;
  int offe = 0;
#pragma unroll
  for (int i = 0; i < NEXP; ++i) offe += (i < e) ? ctrl[i] : 0;

  __shared__ char smem[32768];

  int tid = threadIdx.x;
  int wave = tid >> 6;
  int lane = tid & 63;

  int sr = tid >> 2;
  int kc = (((tid & 3) ^ ((sr >> 1) & 3)) * 8);
  int ia = m0 + sr;      if (ia >= ce) ia = ce - 1;
  int ib = m0 + sr + 64; if (ib >= ce) ib = ce - 1;
  const short* gA0 = hbuf + (size_t)(offe + ia) * HDIM + kc;
  const short* gA1 = hbuf + (size_t)(offe + ib) * HDIM + kc;
  const short* gB0 = w2t + ((size_t)e * DDIM + nt * 128 + sr) * HDIM + kc;
  const short* gB1 = gB0 + (size_t)64 * HDIM;

  f32x4 acc[4][4];
#pragma unroll
  for (int i = 0; i < 4; ++i)
#pragma unroll
    for (int j = 0; j < 4; ++j) acc[i][j] = (f32x4){0.f, 0.f, 0.f, 0.f};

  int wm = (wave >> 1) * 64;
  int wn = (wave & 1) * 64;
  int lr = lane & 15;
  int kswz = ((lane >> 4) * 8) ^ (((lr >> 1) & 3) << 3);

  int colb = nt * 128 + wn;
  float bb[4];
#pragma unroll
  for (int j = 0; j < 4; ++j) bb[j] = b2[e * DDIM + colb + j * 16 + lr];

#define STAGE2(t) do {                                                  \
    int _k = (t) * 32;                                                  \
    char* _lA = smem + (((t) & 1) << 14) + wave * 1024;                 \
    char* _lB = _lA + 8192;                                             \
    async_lds16(gA0 + _k, _lA); async_lds16(gA1 + _k, _lA + 4096);      \
    async_lds16(gB0 + _k, _lB); async_lds16(gB1 + _k, _lB + 4096);      \
  } while (0)

  STAGE2(0);
#pragma unroll
  for (int t = 0; t < 32; ++t) {
    asm volatile("s_waitcnt vmcnt(0)\n\ts_barrier" ::: "memory");
    if (t + 1 < 32) STAGE2(t + 1);
    const short* As = (const short*)(smem + ((t & 1) << 14));
    const short* Bs = As + 4096;
    short8 a[4], b[4];
#pragma unroll
    for (int i = 0; i < 4; ++i) a[i] = *(const short8*)&As[(wm + i * 16 + lr) * 32 + kswz];
#pragma unroll
    for (int j = 0; j < 4; ++j) b[j] = *(const short8*)&Bs[(wn + j * 16 + lr) * 32 + kswz];
    __builtin_amdgcn_s_setprio(1);
#pragma unroll
    for (int i = 0; i < 4; ++i)
#pragma unroll
      for (int j = 0; j < 4; ++j)
        acc[i][j] = __builtin_amdgcn_mfma_f32_16x16x32_bf16(a[i], b[j], acc[i][j], 0, 0, 0);
    __builtin_amdgcn_s_setprio(0);
    asm volatile("s_waitcnt lgkmcnt(0)" ::: "memory");
  }
#undef STAGE2
  __syncthreads();

  // ---- 2-pass LDS epilogue (32 rows/pass): +bias -> bf16 -> short8 stores
  short* ep = (short*)(smem + wave * 4352);
#pragma unroll
  for (int p = 0; p < 2; ++p) {
#pragma unroll
    for (int ii = 0; ii < 2; ++ii) {
#pragma unroll
      for (int j = 0; j < 4; ++j) {
#pragma unroll
        for (int q = 0; q < 4; ++q) {
          int rl = ii * 16 + (lane >> 4) * 4 + q;
          ep[rl * 68 + j * 16 + lr] = f2bf(acc[p * 2 + ii][j][q] + bb[j]);
        }
      }
    }
    __syncthreads();
#pragma unroll
    for (int s = 0; s < 4; ++s) {
      int idx = s * 64 + lane;
      int rl = idx >> 3;
      int c8 = (idx & 7) * 8;
      int gidx = m0 + wm + p * 32 + rl;
      if (gidx < ce) {
        *(short8*)&ybuf[(size_t)(offe + gidx) * DDIM + colb + c8] = *(short8*)&ep[rl * 68 + c8];
      }
    }
    __syncthreads();
  }
}

// ---------------- combine: out[n] = w0*ybuf[slot0] + w1*ybuf[slot1] ----------------
__global__ __launch_bounds__(256) void combine_kernel(
    const short* __restrict__ ybuf, const int* __restrict__ slot_enc,
    const float* __restrict__ wf, const int* __restrict__ ctrl,
    float* __restrict__ out) {
  int wave = threadIdx.x >> 6;
  int lane = threadIdx.x & 63;
  int n = blockIdx.x * 4 + wave;
  int s0 = slot_enc[n * 2], s1 = slot_enc[n * 2 + 1];
  float w0 = wf[n * 2], w1 = wf[n * 2 + 1];
  int e0 = s0 >> 16, e1 = s1 >> 16;
  int off0 = 0, off1 = 0;
#pragma unroll
  for (int i = 0; i < NEXP; ++i) {
    int c = ctrl[i];
    off0 += (i < e0) ? c : 0;
    off1 += (i < e1) ? c : 0;
  }
  int r0 = off0 + (s0 & 0xffff);
  int r1 = off1 + (s1 & 0xffff);
  short8 a = *(const short8*)&ybuf[(size_t)r0 * DDIM + lane * 8];
  short8 b = *(const short8*)&ybuf[(size_t)r1 * DDIM + lane * 8];
  float r[8];
#pragma unroll
  for (int k = 0; k < 8; ++k) r[k] = w0 * bf2f(a[k]) + w1 * bf2f(b[k]);
  float4 o0 = {r[0], r[1], r[2], r[3]};
  float4 o1 = {r[4], r[5], r[6], r[7]};
  *(float4*)&out[(size_t)n * DDIM + lane * 8] = o0;
  *(float4*)&out[(size_t)n * DDIM + lane * 8 + 4] = o1;
}

extern "C" void kernel_launch(void* const* d_in, const int* in_sizes, int n_in,
                              void* d_out, int out_size, void* d_ws, size_t ws_size,
                              hipStream_t stream) {
  const float* x  = (const float*)d_in[0];
  const float* wg = (const float*)d_in[1];
  const float* w1 = (const float*)d_in[2];
  const float* b1 = (const float*)d_in[3];
  const float* w2 = (const float*)d_in[4];
  const float* b2 = (const float*)d_in[5];
  float* out = (float*)d_out;

  char* ws = (char*)d_ws;
  int*   ctrl = (int*)ws;                    // [0..7] counts
  int*   tok  = (int*)(ws + 1024);           // 256 KB
  int*   slot = (int*)(ws + 263168);         // 64 KB
  short* xb   = (short*)(ws + 328704);       // 8 MB
  short* w1t  = (short*)(ws + 8717312);      // 8 MB [E][H][D]
  short* w2t  = (short*)(ws + 17105920);     // 8 MB [E][D][H]
  short* hb   = (short*)(ws + 25494528);     // 32 MB
  short* yb   = (short*)(ws + 328704);       // 16 MB, ALIASES xb+w1t (dead by GEMM2)

  float* out_logits = out + (size_t)NTOK * DDIM;
  float* out_idx = out_logits + (size_t)NTOK * NEXP;
  float* out_w = out_idx + (size_t)NTOK * TOPK;

  prep_kernel<<<10240, 256, 0, stream>>>(w1, w1t, w2, w2t, x, wg,
                                         out_logits, out_idx, out_w, xb, ctrl);
  build_lists<<<16, 512, 0, stream>>>(out_idx, ctrl, tok, slot);

  expert_gemm1<<<4096, 256, 0, stream>>>(xb, w1t, b1, hb, ctrl, tok);
  expert_gemm2<<<2048, 256, 0, stream>>>(hb, w2t, b2, yb, ctrl);
  combine_kernel<<<2048, 256, 0, stream>>>(yb, slot, out_w, ctrl, out);
}

// Round 15
// 122.956 us; speedup vs baseline: 1.1000x; 1.0010x over previous
//
#include <hip/hip_runtime.h>
#include <hip/hip_bf16.h>

#define NTOK 8192
#define DDIM 512
#define HDIM 1024
#define NEXP 8
#define TOPK 2

typedef __attribute__((ext_vector_type(8))) short short8;
typedef __attribute__((ext_vector_type(4))) float f32x4;

// fp32 -> bf16 round-to-nearest-even (finite inputs)
__device__ __forceinline__ short f2bf(float f) {
  union { float f; unsigned u; } v; v.f = f;
  unsigned r = v.u + 0x7fffu + ((v.u >> 16) & 1u);
  return (short)(r >> 16);
}
__device__ __forceinline__ float bf2f(short s) {
  union { unsigned u; float f; } v; v.u = ((unsigned)(unsigned short)s) << 16;
  return v.f;
}

__device__ __forceinline__ void async_lds16(const void* g, void* l) {
  __builtin_amdgcn_global_load_lds(
      (const __attribute__((address_space(1))) unsigned int*)g,
      (__attribute__((address_space(3))) unsigned int*)l,
      16, 0, 0);
}

// fast GELU: v * sigmoid(2u)  (~8 VALU ops); |diff vs erf GELU| < ~1e-3, thr 0.14
__device__ __forceinline__ float gelu_f(float v) {
  float u2 = v * v;
  float z = v * (-1.5957691216f - 0.0713548163f * u2);  // -2u
  float t = __expf(z);
  return v * __builtin_amdgcn_rcpf(1.f + t);
}

// ---------------- prep: weight transposes (blocks 0..8191) + router (blocks 8192..10239) ----------
__global__ __launch_bounds__(256) void prep_kernel(
    const float* __restrict__ w1, short* __restrict__ w1t,
    const float* __restrict__ w2, short* __restrict__ w2t,
    const float* __restrict__ x, const float* __restrict__ wg,
    float* __restrict__ out_logits, float* __restrict__ out_idx,
    float* __restrict__ out_w, short* __restrict__ xb, int* __restrict__ counts) {
  __shared__ float tile[32][33];
  int raw = blockIdx.x;
  if (raw < 8192) {
    int z = raw >> 9;
    int tile_id = raw & 511;
    int R = (z < 8) ? DDIM : HDIM;
    int C = (z < 8) ? HDIM : DDIM;
    const float* s = ((z < 8) ? w1 : w2) + (size_t)(z & 7) * DDIM * HDIM;
    short* d = ((z < 8) ? w1t : w2t) + (size_t)(z & 7) * DDIM * HDIM;
    int tc = (z < 8) ? (tile_id & 31) : (tile_id & 15);
    int tr = (z < 8) ? (tile_id >> 5) : (tile_id >> 4);
    int c0 = tc * 32, r0 = tr * 32;
    int tx = threadIdx.x & 31, ty = threadIdx.x >> 5;
#pragma unroll
    for (int i = 0; i < 4; ++i)
      tile[ty + i * 8][tx] = s[(size_t)(r0 + ty + i * 8) * C + c0 + tx];
    __syncthreads();
#pragma unroll
    for (int i = 0; i < 4; ++i)
      d[(size_t)(c0 + ty + i * 8) * R + r0 + tx] = f2bf(tile[tx][ty + i * 8]);
    return;
  }
  int rb = raw - 8192;
  if (rb == 0 && threadIdx.x < NEXP) counts[threadIdx.x] = 0;
  int wave = threadIdx.x >> 6;
  int lane = threadIdx.x & 63;
  int n = rb * 4 + wave;

  const float* xrow = x + (size_t)n * DDIM;
  const float4* xv = (const float4*)xrow;
  float4 xa = xv[lane * 2], xbv = xv[lane * 2 + 1];
  float xs[8] = {xa.x, xa.y, xa.z, xa.w, xbv.x, xbv.y, xbv.z, xbv.w};

  short8 xc;
#pragma unroll
  for (int j = 0; j < 8; ++j) xc[j] = f2bf(xs[j]);
  *(short8*)(xb + (size_t)n * DDIM + lane * 8) = xc;

  float acc[8] = {0, 0, 0, 0, 0, 0, 0, 0};
#pragma unroll
  for (int j = 0; j < 8; ++j) {
    const float4* wr = (const float4*)(wg + (size_t)(lane * 8 + j) * NEXP);
    float4 w0 = wr[0], w1v = wr[1];
    float xj = xs[j];
    acc[0] += xj * w0.x; acc[1] += xj * w0.y; acc[2] += xj * w0.z; acc[3] += xj * w0.w;
    acc[4] += xj * w1v.x; acc[5] += xj * w1v.y; acc[6] += xj * w1v.z; acc[7] += xj * w1v.w;
  }
#pragma unroll
  for (int m = 32; m >= 1; m >>= 1) {
#pragma unroll
    for (int e = 0; e < 8; ++e) acc[e] += __shfl_xor(acc[e], m);
  }
  if (lane == 0) {
#pragma unroll
    for (int e = 0; e < 8; ++e) out_logits[(size_t)n * NEXP + e] = acc[e];
    int i1 = 0; float v1 = acc[0];
#pragma unroll
    for (int e = 1; e < 8; ++e) if (acc[e] > v1) { v1 = acc[e]; i1 = e; }
    int i2 = -1; float v2 = -3.4e38f;
#pragma unroll
    for (int e = 0; e < 8; ++e) if (e != i1 && acc[e] > v2) { v2 = acc[e]; i2 = e; }
    float ex = expf(v2 - v1);
    float s = 1.f / (1.f + ex);
    out_idx[n * 2] = (float)i1; out_idx[n * 2 + 1] = (float)i2;
    out_w[n * 2] = s; out_w[n * 2 + 1] = ex * s;
  }
}

// ---------------- build per-expert token lists (wave-aggregated atomics) ----------------
__global__ __launch_bounds__(512) void build_lists(
    const float* __restrict__ idxf,
    int* __restrict__ counts, int* __restrict__ tok_list, int* __restrict__ slot_enc) {
  int t = blockIdx.x * 512 + threadIdx.x;
  int lane = threadIdx.x & 63;
  float2 iv = *(const float2*)(idxf + (size_t)t * 2);
  int es[2] = {(int)iv.x, (int)iv.y};
#pragma unroll
  for (int s = 0; s < 2; ++s) {
    int e = es[s];
#pragma unroll
    for (int ex = 0; ex < NEXP; ++ex) {
      unsigned long long m = __ballot(e == ex);
      if (e == ex) {
        int leader = __ffsll(m) - 1;
        int base = 0;
        if (lane == leader) base = atomicAdd(&counts[ex], __popcll(m));
        base = __shfl(base, leader);
        int rank = __popcll(m & ((1ull << lane) - 1ull));
        tok_list[ex * NTOK + base + rank] = t;
        slot_enc[t * 2 + s] = (ex << 16) | (base + rank);
      }
    }
  }
}

// ---------------- GEMM1: h = GELU(gather(x) @ W1[e] + b1[e]) -> bf16 hbuf ----------------
// R12-proven 128x128 structure; LDS shrunk to 32KB (2-pass epilogue) -> 5 blocks/CU.
__global__ __launch_bounds__(256) void expert_gemm1(
    const short* __restrict__ xb, const short* __restrict__ w1t,
    const float* __restrict__ b1, short* __restrict__ hbuf,
    const int* __restrict__ ctrl, const int* __restrict__ tok_list) {
  int raw = blockIdx.x;
  int bid = (raw & 7) * 512 + (raw >> 3);  // bijective: XCD x owns expert x
  int e = bid >> 9;
  int rem = bid & 511;
  int mt = rem >> 3;
  int nt = rem & 7;
  int ce = ctrl[e];
  int m0 = mt * 128;
  if (m0 >= ce) return;
  int offe = 0;
#pragma unroll
  for (int i = 0; i < NEXP; ++i) offe += (i < e) ? ctrl[i] : 0;

  // LDS: 2 staging buffers x 16KB (As 8K | Bs 8K) = 32KB -> 5 blocks/CU.
  // Epilogue reuses [0, 4*4352) in 2 passes of 32 rows.
  __shared__ char smem[32768];

  int tid = threadIdx.x;
  int wave = tid >> 6;
  int lane = tid & 63;

  int sr = tid >> 2;
  // Pre-swizzled source: lane writes LDS chunk (sr, tid&3); fetch the global chunk
  // that belongs there under involution chunk^=((row>>1)&3)
  int kc = (((tid & 3) ^ ((sr >> 1) & 3)) * 8);
  int ia = m0 + sr;      if (ia >= ce) ia = ce - 1;
  int ib = m0 + sr + 64; if (ib >= ce) ib = ce - 1;
  const short* gA0 = xb + (size_t)tok_list[e * NTOK + ia] * DDIM + kc;
  const short* gA1 = xb + (size_t)tok_list[e * NTOK + ib] * DDIM + kc;
  const short* gB0 = w1t + ((size_t)e * HDIM + nt * 128 + sr) * DDIM + kc;
  const short* gB1 = gB0 + (size_t)64 * DDIM;

  f32x4 acc[4][4];
#pragma unroll
  for (int i = 0; i < 4; ++i)
#pragma unroll
    for (int j = 0; j < 4; ++j) acc[i][j] = (f32x4){0.f, 0.f, 0.f, 0.f};

  int wm = (wave >> 1) * 64;
  int wn = (wave & 1) * 64;
  int lr = lane & 15;
  int kswz = ((lane >> 4) * 8) ^ (((lr >> 1) & 3) << 3);

  // Hoist bias loads: latency hides under the K-loop.
  int colb = nt * 128 + wn;
  float bb[4];
#pragma unroll
  for (int j = 0; j < 4; ++j) bb[j] = b1[e * HDIM + colb + j * 16 + lr];

#define STAGE1(t) do {                                                  \
    int _k = (t) * 32;                                                  \
    char* _lA = smem + (((t) & 1) << 14) + wave * 1024;                 \
    char* _lB = _lA + 8192;                                             \
    async_lds16(gA0 + _k, _lA); async_lds16(gA1 + _k, _lA + 4096);      \
    async_lds16(gB0 + _k, _lB); async_lds16(gB1 + _k, _lB + 4096);      \
  } while (0)

  STAGE1(0);
#pragma unroll
  for (int t = 0; t < 16; ++t) {
    // Tile t's DMA (all waves) landed once every wave passes this barrier.
    asm volatile("s_waitcnt vmcnt(0)\n\ts_barrier" ::: "memory");
    // Overwriting buf[(t+1)&1] (read at t-1) is safe: every wave drained
    // lgkmcnt(0) at the end of iter t-1, BEFORE arriving at the barrier above.
    if (t + 1 < 16) STAGE1(t + 1);
    const short* As = (const short*)(smem + ((t & 1) << 14));
    const short* Bs = As + 4096;
    short8 a[4], b[4];
#pragma unroll
    for (int i = 0; i < 4; ++i) a[i] = *(const short8*)&As[(wm + i * 16 + lr) * 32 + kswz];
#pragma unroll
    for (int j = 0; j < 4; ++j) b[j] = *(const short8*)&Bs[(wn + j * 16 + lr) * 32 + kswz];
    // Compiler emits counted lgkmcnt before each first use (read/MFMA interleave).
    __builtin_amdgcn_s_setprio(1);
#pragma unroll
    for (int i = 0; i < 4; ++i)
#pragma unroll
      for (int j = 0; j < 4; ++j)
        acc[i][j] = __builtin_amdgcn_mfma_f32_16x16x32_bf16(a[i], b[j], acc[i][j], 0, 0, 0);
    __builtin_amdgcn_s_setprio(0);
    // Invariant: this wave's ds_reads are SERVICED before it reaches the next barrier.
    asm volatile("s_waitcnt lgkmcnt(0)" ::: "memory");
  }
#undef STAGE1
  __syncthreads();  // all K-loop reads done before epilogue reuses smem

  // ---- 2-pass LDS epilogue (32 rows/pass): GELU -> bf16 -> [32][68]/wave -> short8 stores
  short* ep = (short*)(smem + wave * 4352);
#pragma unroll
  for (int p = 0; p < 2; ++p) {
#pragma unroll
    for (int ii = 0; ii < 2; ++ii) {
#pragma unroll
      for (int j = 0; j < 4; ++j) {
#pragma unroll
        for (int q = 0; q < 4; ++q) {
          int rl = ii * 16 + (lane >> 4) * 4 + q;
          ep[rl * 68 + j * 16 + lr] = f2bf(gelu_f(acc[p * 2 + ii][j][q] + bb[j]));
        }
      }
    }
    __syncthreads();
#pragma unroll
    for (int s = 0; s < 4; ++s) {
      int idx = s * 64 + lane;
      int rl = idx >> 3;
      int c8 = (idx & 7) * 8;
      int gidx = m0 + wm + p * 32 + rl;
      if (gidx < ce) {
        *(short8*)&hbuf[(size_t)(offe + gidx) * HDIM + colb + c8] = *(short8*)&ep[rl * 68 + c8];
      }
    }
    __syncthreads();
  }
}

// ---------------- GEMM2: ybuf = (h @ W2[e] + b2[e]) in bf16 (per expert-slot row) ----------------
__global__ __launch_bounds__(256) void expert_gemm2(
    const short* __restrict__ hbuf, const short* __restrict__ w2t,
    const float* __restrict__ b2, short* __restrict__ ybuf,
    const int* __restrict__ ctrl) {
  int raw = blockIdx.x;
  int bid = (raw & 7) * 256 + (raw >> 3);  // XCD x owns expert x
  int e = bid >> 8;
  int rem = bid & 255;
  int mt = rem >> 2;
  int nt = rem & 3;
  int ce = ctrl[e];
  int m0 = mt * 128;
  if (m0 >= ce) return;
  int offe = 0;
#pragma unroll
  for (int i = 0; i < NEXP; ++i) offe += (i < e) ? ctrl[i] : 0;

  __shared__ char smem[32768];

  int tid = threadIdx.x;
  int wave = tid >> 6;
  int lane = tid & 63;

  int sr = tid >> 2;
  int kc = (((tid & 3) ^ ((sr >> 1) & 3)) * 8);
  int ia = m0 + sr;      if (ia >= ce) ia = ce - 1;
  int ib = m0 + sr + 64; if (ib >= ce) ib = ce - 1;
  const short* gA0 = hbuf + (size_t)(offe + ia) * HDIM + kc;
  const short* gA1 = hbuf + (size_t)(offe + ib) * HDIM + kc;
  const short* gB0 = w2t + ((size_t)e * DDIM + nt * 128 + sr) * HDIM + kc;
  const short* gB1 = gB0 + (size_t)64 * HDIM;

  f32x4 acc[4][4];
#pragma unroll
  for (int i = 0; i < 4; ++i)
#pragma unroll
    for (int j = 0; j < 4; ++j) acc[i][j] = (f32x4){0.f, 0.f, 0.f, 0.f};

  int wm = (wave >> 1) * 64;
  int wn = (wave & 1) * 64;
  int lr = lane & 15;
  int kswz = ((lane >> 4) * 8) ^ (((lr >> 1) & 3) << 3);

  int colb = nt * 128 + wn;
  float bb[4];
#pragma unroll
  for (int j = 0; j < 4; ++j) bb[j] = b2[e * DDIM + colb + j * 16 + lr];

#define STAGE2(t) do {                                                  \
    int _k = (t) * 32;                                                  \
    char* _lA = smem + (((t) & 1) << 14) + wave * 1024;                 \
    char* _lB = _lA + 8192;                                             \
    async_lds16(gA0 + _k, _lA); async_lds16(gA1 + _k, _lA + 4096);      \
    async_lds16(gB0 + _k, _lB); async_lds16(gB1 + _k, _lB + 4096);      \
  } while (0)

  STAGE2(0);
#pragma unroll
  for (int t = 0; t < 32; ++t) {
    asm volatile("s_waitcnt vmcnt(0)\n\ts_barrier" ::: "memory");
    if (t + 1 < 32) STAGE2(t + 1);
    const short* As = (const short*)(smem + ((t & 1) << 14));
    const short* Bs = As + 4096;
    short8 a[4], b[4];
#pragma unroll
    for (int i = 0; i < 4; ++i) a[i] = *(const short8*)&As[(wm + i * 16 + lr) * 32 + kswz];
#pragma unroll
    for (int j = 0; j < 4; ++j) b[j] = *(const short8*)&Bs[(wn + j * 16 + lr) * 32 + kswz];
    __builtin_amdgcn_s_setprio(1);
#pragma unroll
    for (int i = 0; i < 4; ++i)
#pragma unroll
      for (int j = 0; j < 4; ++j)
        acc[i][j] = __builtin_amdgcn_mfma_f32_16x16x32_bf16(a[i], b[j], acc[i][j], 0, 0, 0);
    __builtin_amdgcn_s_setprio(0);
    asm volatile("s_waitcnt lgkmcnt(0)" ::: "memory");
  }
#undef STAGE2
  __syncthreads();

  // ---- 2-pass LDS epilogue (32 rows/pass): +bias -> bf16 -> short8 stores
  short* ep = (short*)(smem + wave * 4352);
#pragma unroll
  for (int p = 0; p < 2; ++p) {
#pragma unroll
    for (int ii = 0; ii < 2; ++ii) {
#pragma unroll
      for (int j = 0; j < 4; ++j) {
#pragma unroll
        for (int q = 0; q < 4; ++q) {
          int rl = ii * 16 + (lane >> 4) * 4 + q;
          ep[rl * 68 + j * 16 + lr] = f2bf(acc[p * 2 + ii][j][q] + bb[j]);
        }
      }
    }
    __syncthreads();
#pragma unroll
    for (int s = 0; s < 4; ++s) {
      int idx = s * 64 + lane;
      int rl = idx >> 3;
      int c8 = (idx & 7) * 8;
      int gidx = m0 + wm + p * 32 + rl;
      if (gidx < ce) {
        *(short8*)&ybuf[(size_t)(offe + gidx) * DDIM + colb + c8] = *(short8*)&ep[rl * 68 + c8];
      }
    }
    __syncthreads();
  }
}

// ---------------- combine: out[n] = w0*ybuf[slot0] + w1*ybuf[slot1] ----------------
__global__ __launch_bounds__(256) void combine_kernel(
    const short* __restrict__ ybuf, const int* __restrict__ slot_enc,
    const float* __restrict__ wf, const int* __restrict__ ctrl,
    float* __restrict__ out) {
  int wave = threadIdx.x >> 6;
  int lane = threadIdx.x & 63;
  int n = blockIdx.x * 4 + wave;
  int s0 = slot_enc[n * 2], s1 = slot_enc[n * 2 + 1];
  float w0 = wf[n * 2], w1 = wf[n * 2 + 1];
  int e0 = s0 >> 16, e1 = s1 >> 16;
  int off0 = 0, off1 = 0;
#pragma unroll
  for (int i = 0; i < NEXP; ++i) {
    int c = ctrl[i];
    off0 += (i < e0) ? c : 0;
    off1 += (i < e1) ? c : 0;
  }
  int r0 = off0 + (s0 & 0xffff);
  int r1 = off1 + (s1 & 0xffff);
  short8 a = *(const short8*)&ybuf[(size_t)r0 * DDIM + lane * 8];
  short8 b = *(const short8*)&ybuf[(size_t)r1 * DDIM + lane * 8];
  float r[8];
#pragma unroll
  for (int k = 0; k < 8; ++k) r[k] = w0 * bf2f(a[k]) + w1 * bf2f(b[k]);
  float4 o0 = {r[0], r[1], r[2], r[3]};
  float4 o1 = {r[4], r[5], r[6], r[7]};
  *(float4*)&out[(size_t)n * DDIM + lane * 8] = o0;
  *(float4*)&out[(size_t)n * DDIM + lane * 8 + 4] = o1;
}

extern "C" void kernel_launch(void* const* d_in, const int* in_sizes, int n_in,
                              void* d_out, int out_size, void* d_ws, size_t ws_size,
                              hipStream_t stream) {
  const float* x  = (const float*)d_in[0];
  const float* wg = (const float*)d_in[1];
  const float* w1 = (const float*)d_in[2];
  const float* b1 = (const float*)d_in[3];
  const float* w2 = (const float*)d_in[4];
  const float* b2 = (const float*)d_in[5];
  float* out = (float*)d_out;

  char* ws = (char*)d_ws;
  int*   ctrl = (int*)ws;                    // [0..7] counts
  int*   tok  = (int*)(ws + 1024);           // 256 KB
  int*   slot = (int*)(ws + 263168);         // 64 KB
  short* xb   = (short*)(ws + 328704);       // 8 MB
  short* w1t  = (short*)(ws + 8717312);      // 8 MB [E][H][D]
  short* w2t  = (short*)(ws + 17105920);     // 8 MB [E][D][H]
  short* hb   = (short*)(ws + 25494528);     // 32 MB
  short* yb   = (short*)(ws + 328704);       // 16 MB, ALIASES xb+w1t (dead by GEMM2)

  float* out_logits = out + (size_t)NTOK * DDIM;
  float* out_idx = out_logits + (size_t)NTOK * NEXP;
  float* out_w = out_idx + (size_t)NTOK * TOPK;

  prep_kernel<<<10240, 256, 0, stream>>>(w1, w1t, w2, w2t, x, wg,
                                         out_logits, out_idx, out_w, xb, ctrl);
  build_lists<<<16, 512, 0, stream>>>(out_idx, ctrl, tok, slot);

  expert_gemm1<<<4096, 256, 0, stream>>>(xb, w1t, b1, hb, ctrl, tok);
  expert_gemm2<<<2048, 256, 0, stream>>>(hb, w2t, b2, yb, ctrl);
  combine_kernel<<<2048, 256, 0, stream>>>(yb, slot, out_w, ctrl, out);
}

// Round 16
// 122.953 us; speedup vs baseline: 1.1000x; 1.0000x over previous
//
#include <hip/hip_runtime.h>
#include <hip/hip_bf16.h>

#define NTOK 8192
#define DDIM 512
#define HDIM 1024
#define NEXP 8
#define TOPK 2

typedef __attribute__((ext_vector_type(8))) short short8;
typedef __attribute__((ext_vector_type(4))) short short4v;
typedef __attribute__((ext_vector_type(4))) float f32x4;

// fp32 -> bf16 round-to-nearest-even (finite inputs)
__device__ __forceinline__ short f2bf(float f) {
  union { float f; unsigned u; } v; v.f = f;
  unsigned r = v.u + 0x7fffu + ((v.u >> 16) & 1u);
  return (short)(r >> 16);
}
__device__ __forceinline__ float bf2f(short s) {
  union { unsigned u; float f; } v; v.u = ((unsigned)(unsigned short)s) << 16;
  return v.f;
}

__device__ __forceinline__ void async_lds16(const void* g, void* l) {
  __builtin_amdgcn_global_load_lds(
      (const __attribute__((address_space(1))) unsigned int*)g,
      (__attribute__((address_space(3))) unsigned int*)l,
      16, 0, 0);
}

// fast GELU: v * sigmoid(2u)  (~8 VALU ops); |diff vs erf GELU| < ~1e-3, thr 0.14
__device__ __forceinline__ float gelu_f(float v) {
  float u2 = v * v;
  float z = v * (-1.5957691216f - 0.0713548163f * u2);  // -2u
  float t = __expf(z);
  return v * __builtin_amdgcn_rcpf(1.f + t);
}

// ---------------- prep: weight transposes (blocks 0..8191) + router (blocks 8192..10239) ----------
// Transpose vectorized: 1 float4 load + 1 short4 store per thread (was 4+4 scalar).
__global__ __launch_bounds__(256) void prep_kernel(
    const float* __restrict__ w1, short* __restrict__ w1t,
    const float* __restrict__ w2, short* __restrict__ w2t,
    const float* __restrict__ x, const float* __restrict__ wg,
    float* __restrict__ out_logits, float* __restrict__ out_idx,
    float* __restrict__ out_w, short* __restrict__ xb, int* __restrict__ counts) {
  __shared__ float tile[32][33];
  int raw = blockIdx.x;
  if (raw < 8192) {
    int z = raw >> 9;
    int tile_id = raw & 511;
    int R = (z < 8) ? DDIM : HDIM;
    int C = (z < 8) ? HDIM : DDIM;
    const float* s = ((z < 8) ? w1 : w2) + (size_t)(z & 7) * DDIM * HDIM;
    short* d = ((z < 8) ? w1t : w2t) + (size_t)(z & 7) * DDIM * HDIM;
    int tc = (z < 8) ? (tile_id & 31) : (tile_id & 15);
    int tr = (z < 8) ? (tile_id >> 5) : (tile_id >> 4);
    int c0 = tc * 32, r0 = tr * 32;
    int tid = threadIdx.x;
    // load: row ty, 4 cols; wave covers 8 rows x 128B contiguous; LDS 2-way (free)
    int ty = tid >> 3, tx4 = (tid & 7) * 4;
    float4 lv = *(const float4*)(s + (size_t)(r0 + ty) * C + c0 + tx4);
    tile[ty][tx4] = lv.x; tile[ty][tx4 + 1] = lv.y;
    tile[ty][tx4 + 2] = lv.z; tile[ty][tx4 + 3] = lv.w;
    __syncthreads();
    // store: col sc, 4 consecutive r; 8-lane group = 64B contiguous; LDS 2-way (free)
    int sc = tid >> 3, rs = (tid & 7) * 4;
    short4v ov;
#pragma unroll
    for (int j = 0; j < 4; ++j) ov[j] = f2bf(tile[rs + j][sc]);
    *(short4v*)(d + (size_t)(c0 + sc) * R + r0 + rs) = ov;
    return;
  }
  int rb = raw - 8192;
  if (rb == 0 && threadIdx.x < NEXP) counts[threadIdx.x] = 0;
  int wave = threadIdx.x >> 6;
  int lane = threadIdx.x & 63;
  int n = rb * 4 + wave;

  const float* xrow = x + (size_t)n * DDIM;
  const float4* xv = (const float4*)xrow;
  float4 xa = xv[lane * 2], xbv = xv[lane * 2 + 1];
  float xs[8] = {xa.x, xa.y, xa.z, xa.w, xbv.x, xbv.y, xbv.z, xbv.w};

  short8 xc;
#pragma unroll
  for (int j = 0; j < 8; ++j) xc[j] = f2bf(xs[j]);
  *(short8*)(xb + (size_t)n * DDIM + lane * 8) = xc;

  float acc[8] = {0, 0, 0, 0, 0, 0, 0, 0};
#pragma unroll
  for (int j = 0; j < 8; ++j) {
    const float4* wr = (const float4*)(wg + (size_t)(lane * 8 + j) * NEXP);
    float4 w0 = wr[0], w1v = wr[1];
    float xj = xs[j];
    acc[0] += xj * w0.x; acc[1] += xj * w0.y; acc[2] += xj * w0.z; acc[3] += xj * w0.w;
    acc[4] += xj * w1v.x; acc[5] += xj * w1v.y; acc[6] += xj * w1v.z; acc[7] += xj * w1v.w;
  }
#pragma unroll
  for (int m = 32; m >= 1; m >>= 1) {
#pragma unroll
    for (int e = 0; e < 8; ++e) acc[e] += __shfl_xor(acc[e], m);
  }
  if (lane == 0) {
#pragma unroll
    for (int e = 0; e < 8; ++e) out_logits[(size_t)n * NEXP + e] = acc[e];
    int i1 = 0; float v1 = acc[0];
#pragma unroll
    for (int e = 1; e < 8; ++e) if (acc[e] > v1) { v1 = acc[e]; i1 = e; }
    int i2 = -1; float v2 = -3.4e38f;
#pragma unroll
    for (int e = 0; e < 8; ++e) if (e != i1 && acc[e] > v2) { v2 = acc[e]; i2 = e; }
    float ex = expf(v2 - v1);
    float s = 1.f / (1.f + ex);
    out_idx[n * 2] = (float)i1; out_idx[n * 2 + 1] = (float)i2;
    out_w[n * 2] = s; out_w[n * 2 + 1] = ex * s;
  }
}

// ---------------- build per-expert token lists (wave-aggregated atomics) ----------------
__global__ __launch_bounds__(512) void build_lists(
    const float* __restrict__ idxf,
    int* __restrict__ counts, int* __restrict__ tok_list, int* __restrict__ slot_enc) {
  int t = blockIdx.x * 512 + threadIdx.x;
  int lane = threadIdx.x & 63;
  float2 iv = *(const float2*)(idxf + (size_t)t * 2);
  int es[2] = {(int)iv.x, (int)iv.y};
#pragma unroll
  for (int s = 0; s < 2; ++s) {
    int e = es[s];
#pragma unroll
    for (int ex = 0; ex < NEXP; ++ex) {
      unsigned long long m = __ballot(e == ex);
      if (e == ex) {
        int leader = __ffsll(m) - 1;
        int base = 0;
        if (lane == leader) base = atomicAdd(&counts[ex], __popcll(m));
        base = __shfl(base, leader);
        int rank = __popcll(m & ((1ull << lane) - 1ull));
        tok_list[ex * NTOK + base + rank] = t;
        slot_enc[t * 2 + s] = (ex << 16) | (base + rank);
      }
    }
  }
}

// ---------------- GEMM1: h = GELU(gather(x) @ W1[e] + b1[e]) -> bf16 hbuf ----------------
// R12-proven 128x128 structure; 32KB LDS (2-pass epilogue) -> 5 blocks/CU.
__global__ __launch_bounds__(256) void expert_gemm1(
    const short* __restrict__ xb, const short* __restrict__ w1t,
    const float* __restrict__ b1, short* __restrict__ hbuf,
    const int* __restrict__ ctrl, const int* __restrict__ tok_list) {
  int raw = blockIdx.x;
  int bid = (raw & 7) * 512 + (raw >> 3);  // bijective: XCD x owns expert x
  int e = bid >> 9;
  int rem = bid & 511;
  int mt = rem >> 3;
  int nt = rem & 7;
  int ce = ctrl[e];
  int m0 = mt * 128;
  if (m0 >= ce) return;
  int offe = 0;
#pragma unroll
  for (int i = 0; i < NEXP; ++i) offe += (i < e) ? ctrl[i] : 0;

  __shared__ char smem[32768];

  int tid = threadIdx.x;
  int wave = tid >> 6;
  int lane = tid & 63;

  int sr = tid >> 2;
  int kc = (((tid & 3) ^ ((sr >> 1) & 3)) * 8);
  int ia = m0 + sr;      if (ia >= ce) ia = ce - 1;
  int ib = m0 + sr + 64; if (ib >= ce) ib = ce - 1;
  const short* gA0 = xb + (size_t)tok_list[e * NTOK + ia] * DDIM + kc;
  const short* gA1 = xb + (size_t)tok_list[e * NTOK + ib] * DDIM + kc;
  const short* gB0 = w1t + ((size_t)e * HDIM + nt * 128 + sr) * DDIM + kc;
  const short* gB1 = gB0 + (size_t)64 * DDIM;

  f32x4 acc[4][4];
#pragma unroll
  for (int i = 0; i < 4; ++i)
#pragma unroll
    for (int j = 0; j < 4; ++j) acc[i][j] = (f32x4){0.f, 0.f, 0.f, 0.f};

  int wm = (wave >> 1) * 64;
  int wn = (wave & 1) * 64;
  int lr = lane & 15;
  int kswz = ((lane >> 4) * 8) ^ (((lr >> 1) & 3) << 3);

  int colb = nt * 128 + wn;
  float bb[4];
#pragma unroll
  for (int j = 0; j < 4; ++j) bb[j] = b1[e * HDIM + colb + j * 16 + lr];

#define STAGE1(t) do {                                                  \
    int _k = (t) * 32;                                                  \
    char* _lA = smem + (((t) & 1) << 14) + wave * 1024;                 \
    char* _lB = _lA + 8192;                                             \
    async_lds16(gA0 + _k, _lA); async_lds16(gA1 + _k, _lA + 4096);      \
    async_lds16(gB0 + _k, _lB); async_lds16(gB1 + _k, _lB + 4096);      \
  } while (0)

  STAGE1(0);
#pragma unroll
  for (int t = 0; t < 16; ++t) {
    asm volatile("s_waitcnt vmcnt(0)\n\ts_barrier" ::: "memory");
    if (t + 1 < 16) STAGE1(t + 1);
    const short* As = (const short*)(smem + ((t & 1) << 14));
    const short* Bs = As + 4096;
    short8 a[4], b[4];
#pragma unroll
    for (int i = 0; i < 4; ++i) a[i] = *(const short8*)&As[(wm + i * 16 + lr) * 32 + kswz];
#pragma unroll
    for (int j = 0; j < 4; ++j) b[j] = *(const short8*)&Bs[(wn + j * 16 + lr) * 32 + kswz];
    __builtin_amdgcn_s_setprio(1);
#pragma unroll
    for (int i = 0; i < 4; ++i)
#pragma unroll
      for (int j = 0; j < 4; ++j)
        acc[i][j] = __builtin_amdgcn_mfma_f32_16x16x32_bf16(a[i], b[j], acc[i][j], 0, 0, 0);
    __builtin_amdgcn_s_setprio(0);
    asm volatile("s_waitcnt lgkmcnt(0)" ::: "memory");
  }
#undef STAGE1
  __syncthreads();

  // ---- 2-pass LDS epilogue (32 rows/pass): GELU -> bf16 -> [32][68]/wave -> short8 stores
  short* ep = (short*)(smem + wave * 4352);
#pragma unroll
  for (int p = 0; p < 2; ++p) {
#pragma unroll
    for (int ii = 0; ii < 2; ++ii) {
#pragma unroll
      for (int j = 0; j < 4; ++j) {
#pragma unroll
        for (int q = 0; q < 4; ++q) {
          int rl = ii * 16 + (lane >> 4) * 4 + q;
          ep[rl * 68 + j * 16 + lr] = f2bf(gelu_f(acc[p * 2 + ii][j][q] + bb[j]));
        }
      }
    }
    __syncthreads();
#pragma unroll
    for (int s = 0; s < 4; ++s) {
      int idx = s * 64 + lane;
      int rl = idx >> 3;
      int c8 = (idx & 7) * 8;
      int gidx = m0 + wm + p * 32 + rl;
      if (gidx < ce) {
        *(short8*)&hbuf[(size_t)(offe + gidx) * HDIM + colb + c8] = *(short8*)&ep[rl * 68 + c8];
      }
    }
    __syncthreads();
  }
}

// ---------------- GEMM2: ybuf = (h @ W2[e] + b2[e]) in bf16 (per expert-slot row) ----------------
__global__ __launch_bounds__(256) void expert_gemm2(
    const short* __restrict__ hbuf, const short* __restrict__ w2t,
    const float* __restrict__ b2, short* __restrict__ ybuf,
    const int* __restrict__ ctrl) {
  int raw = blockIdx.x;
  int bid = (raw & 7) * 256 + (raw >> 3);  // XCD x owns expert x
  int e = bid >> 8;
  int rem = bid & 255;
  int mt = rem >> 2;
  int nt = rem & 3;
  int ce = ctrl[e];
  int m0 = mt * 128;
  if (m0 >= ce) return;
  int offe = 0;
#pragma unroll
  for (int i = 0; i < NEXP; ++i) offe += (i < e) ? ctrl[i] : 0;

  __shared__ char smem[32768];

  int tid = threadIdx.x;
  int wave = tid >> 6;
  int lane = tid & 63;

  int sr = tid >> 2;
  int kc = (((tid & 3) ^ ((sr >> 1) & 3)) * 8);
  int ia = m0 + sr;      if (ia >= ce) ia = ce - 1;
  int ib = m0 + sr + 64; if (ib >= ce) ib = ce - 1;
  const short* gA0 = hbuf + (size_t)(offe + ia) * HDIM + kc;
  const short* gA1 = hbuf + (size_t)(offe + ib) * HDIM + kc;
  const short* gB0 = w2t + ((size_t)e * DDIM + nt * 128 + sr) * HDIM + kc;
  const short* gB1 = gB0 + (size_t)64 * HDIM;

  f32x4 acc[4][4];
#pragma unroll
  for (int i = 0; i < 4; ++i)
#pragma unroll
    for (int j = 0; j < 4; ++j) acc[i][j] = (f32x4){0.f, 0.f, 0.f, 0.f};

  int wm = (wave >> 1) * 64;
  int wn = (wave & 1) * 64;
  int lr = lane & 15;
  int kswz = ((lane >> 4) * 8) ^ (((lr >> 1) & 3) << 3);

  int colb = nt * 128 + wn;
  float bb[4];
#pragma unroll
  for (int j = 0; j < 4; ++j) bb[j] = b2[e * DDIM + colb + j * 16 + lr];

#define STAGE2(t) do {                                                  \
    int _k = (t) * 32;                                                  \
    char* _lA = smem + (((t) & 1) << 14) + wave * 1024;                 \
    char* _lB = _lA + 8192;                                             \
    async_lds16(gA0 + _k, _lA); async_lds16(gA1 + _k, _lA + 4096);      \
    async_lds16(gB0 + _k, _lB); async_lds16(gB1 + _k, _lB + 4096);      \
  } while (0)

  STAGE2(0);
#pragma unroll
  for (int t = 0; t < 32; ++t) {
    asm volatile("s_waitcnt vmcnt(0)\n\ts_barrier" ::: "memory");
    if (t + 1 < 32) STAGE2(t + 1);
    const short* As = (const short*)(smem + ((t & 1) << 14));
    const short* Bs = As + 4096;
    short8 a[4], b[4];
#pragma unroll
    for (int i = 0; i < 4; ++i) a[i] = *(const short8*)&As[(wm + i * 16 + lr) * 32 + kswz];
#pragma unroll
    for (int j = 0; j < 4; ++j) b[j] = *(const short8*)&Bs[(wn + j * 16 + lr) * 32 + kswz];
    __builtin_amdgcn_s_setprio(1);
#pragma unroll
    for (int i = 0; i < 4; ++i)
#pragma unroll
      for (int j = 0; j < 4; ++j)
        acc[i][j] = __builtin_amdgcn_mfma_f32_16x16x32_bf16(a[i], b[j], acc[i][j], 0, 0, 0);
    __builtin_amdgcn_s_setprio(0);
    asm volatile("s_waitcnt lgkmcnt(0)" ::: "memory");
  }
#undef STAGE2
  __syncthreads();

  // ---- 2-pass LDS epilogue (32 rows/pass): +bias -> bf16 -> short8 stores
  short* ep = (short*)(smem + wave * 4352);
#pragma unroll
  for (int p = 0; p < 2; ++p) {
#pragma unroll
    for (int ii = 0; ii < 2; ++ii) {
#pragma unroll
      for (int j = 0; j < 4; ++j) {
#pragma unroll
        for (int q = 0; q < 4; ++q) {
          int rl = ii * 16 + (lane >> 4) * 4 + q;
          ep[rl * 68 + j * 16 + lr] = f2bf(acc[p * 2 + ii][j][q] + bb[j]);
        }
      }
    }
    __syncthreads();
#pragma unroll
    for (int s = 0; s < 4; ++s) {
      int idx = s * 64 + lane;
      int rl = idx >> 3;
      int c8 = (idx & 7) * 8;
      int gidx = m0 + wm + p * 32 + rl;
      if (gidx < ce) {
        *(short8*)&ybuf[(size_t)(offe + gidx) * DDIM + colb + c8] = *(short8*)&ep[rl * 68 + c8];
      }
    }
    __syncthreads();
  }
}

// ---------------- combine: out[n] = w0*ybuf[slot0] + w1*ybuf[slot1] ----------------
__global__ __launch_bounds__(256) void combine_kernel(
    const short* __restrict__ ybuf, const int* __restrict__ slot_enc,
    const float* __restrict__ wf, const int* __restrict__ ctrl,
    float* __restrict__ out) {
  int wave = threadIdx.x >> 6;
  int lane = threadIdx.x & 63;
  int n = blockIdx.x * 4 + wave;
  int s0 = slot_enc[n * 2], s1 = slot_enc[n * 2 + 1];
  float w0 = wf[n * 2], w1 = wf[n * 2 + 1];
  int e0 = s0 >> 16, e1 = s1 >> 16;
  int off0 = 0, off1 = 0;
#pragma unroll
  for (int i = 0; i < NEXP; ++i) {
    int c = ctrl[i];
    off0 += (i < e0) ? c : 0;
    off1 += (i < e1) ? c : 0;
  }
  int r0 = off0 + (s0 & 0xffff);
  int r1 = off1 + (s1 & 0xffff);
  short8 a = *(const short8*)&ybuf[(size_t)r0 * DDIM + lane * 8];
  short8 b = *(const short8*)&ybuf[(size_t)r1 * DDIM + lane * 8];
  float r[8];
#pragma unroll
  for (int k = 0; k < 8; ++k) r[k] = w0 * bf2f(a[k]) + w1 * bf2f(b[k]);
  float4 o0 = {r[0], r[1], r[2], r[3]};
  float4 o1 = {r[4], r[5], r[6], r[7]};
  *(float4*)&out[(size_t)n * DDIM + lane * 8] = o0;
  *(float4*)&out[(size_t)n * DDIM + lane * 8 + 4] = o1;
}

extern "C" void kernel_launch(void* const* d_in, const int* in_sizes, int n_in,
                              void* d_out, int out_size, void* d_ws, size_t ws_size,
                              hipStream_t stream) {
  const float* x  = (const float*)d_in[0];
  const float* wg = (const float*)d_in[1];
  const float* w1 = (const float*)d_in[2];
  const float* b1 = (const float*)d_in[3];
  const float* w2 = (const float*)d_in[4];
  const float* b2 = (const float*)d_in[5];
  float* out = (float*)d_out;

  char* ws = (char*)d_ws;
  int*   ctrl = (int*)ws;                    // [0..7] counts
  int*   tok  = (int*)(ws + 1024);           // 256 KB
  int*   slot = (int*)(ws + 263168);         // 64 KB
  short* xb   = (short*)(ws + 328704);       // 8 MB
  short* w1t  = (short*)(ws + 8717312);      // 8 MB [E][H][D]
  short* w2t  = (short*)(ws + 17105920);     // 8 MB [E][D][H]
  short* hb   = (short*)(ws + 25494528);     // 32 MB
  short* yb   = (short*)(ws + 328704);       // 16 MB, ALIASES xb+w1t (dead by GEMM2)

  float* out_logits = out + (size_t)NTOK * DDIM;
  float* out_idx = out_logits + (size_t)NTOK * NEXP;
  float* out_w = out_idx + (size_t)NTOK * TOPK;

  prep_kernel<<<10240, 256, 0, stream>>>(w1, w1t, w2, w2t, x, wg,
                                         out_logits, out_idx, out_w, xb, ctrl);
  build_lists<<<16, 512, 0, stream>>>(out_idx, ctrl, tok, slot);

  expert_gemm1<<<4096, 256, 0, stream>>>(xb, w1t, b1, hb, ctrl, tok);
  expert_gemm2<<<2048, 256, 0, stream>>>(hb, w2t, b2, yb, ctrl);
  combine_kernel<<<2048, 256, 0, stream>>>(yb, slot, out_w, ctrl, out);
}